// Round 1
// baseline (194.784 us; speedup 1.0000x reference)
//
#include <hip/hip_runtime.h>

#define DDIM 128
#define ACC_BLOCKS 1024

// ---------------- Kernel 1: Wh[t] = W @ h[t], Mh[t] = M @ h[t] ----------------
// Thread d (0..127) computes output feature d for 8 rows held in registers.
// h-row loads are wave-uniform -> compiler emits scalar loads; W/M rows are
// per-lane float4 (L1/L2 resident, 128 KB total).
__global__ __launch_bounds__(128) void precompute_wh_mh(
    const float* __restrict__ impact,
    const float* __restrict__ W,
    const float* __restrict__ Mm,
    float* __restrict__ Wh,
    float* __restrict__ Mh,
    int T)
{
    const int d = threadIdx.x;                 // output feature
    const int row0 = blockIdx.x * 8;
    const float4* __restrict__ W4 = reinterpret_cast<const float4*>(W) + (size_t)d * 32;
    const float4* __restrict__ M4 = reinterpret_cast<const float4*>(Mm) + (size_t)d * 32;

    float accW[8], accM[8];
#pragma unroll
    for (int r = 0; r < 8; ++r) { accW[r] = 0.f; accM[r] = 0.f; }

    if (row0 + 8 <= T) {
        for (int kq = 0; kq < 32; ++kq) {
            const float4 wv = W4[kq];
            const float4 mv = M4[kq];
#pragma unroll
            for (int r = 0; r < 8; ++r) {
                const float4 hv = *reinterpret_cast<const float4*>(
                    impact + (size_t)(row0 + r) * DDIM + kq * 4);
                accW[r] = fmaf(hv.x, wv.x, accW[r]);
                accW[r] = fmaf(hv.y, wv.y, accW[r]);
                accW[r] = fmaf(hv.z, wv.z, accW[r]);
                accW[r] = fmaf(hv.w, wv.w, accW[r]);
                accM[r] = fmaf(hv.x, mv.x, accM[r]);
                accM[r] = fmaf(hv.y, mv.y, accM[r]);
                accM[r] = fmaf(hv.z, mv.z, accM[r]);
                accM[r] = fmaf(hv.w, mv.w, accM[r]);
            }
        }
#pragma unroll
        for (int r = 0; r < 8; ++r) {
            Wh[(size_t)(row0 + r) * DDIM + d] = accW[r];
            Mh[(size_t)(row0 + r) * DDIM + d] = accM[r];
        }
    } else {
        const int rmax = T - row0;
        if (rmax <= 0) return;
        for (int kq = 0; kq < 32; ++kq) {
            const float4 wv = W4[kq];
            const float4 mv = M4[kq];
            for (int r = 0; r < rmax; ++r) {
                const float4 hv = *reinterpret_cast<const float4*>(
                    impact + (size_t)(row0 + r) * DDIM + kq * 4);
                accW[r] = fmaf(hv.x, wv.x, accW[r]);
                accW[r] = fmaf(hv.y, wv.y, accW[r]);
                accW[r] = fmaf(hv.z, wv.z, accW[r]);
                accW[r] = fmaf(hv.w, wv.w, accW[r]);
                accM[r] = fmaf(hv.x, mv.x, accM[r]);
                accM[r] = fmaf(hv.y, mv.y, accM[r]);
                accM[r] = fmaf(hv.z, mv.z, accM[r]);
                accM[r] = fmaf(hv.w, mv.w, accM[r]);
            }
        }
        for (int r = 0; r < rmax; ++r) {
            Wh[(size_t)(row0 + r) * DDIM + d] = accW[r];
            Mh[(size_t)(row0 + r) * DDIM + d] = accM[r];
        }
    }
}

// ---------------- Kernel 2: per-node gather-sum + relu + block partial ----------------
// Each block: contiguous node range, split across 4 waves. Lane holds float2 of
// features (wave reads exactly one 512B row per gather -> fully coalesced).
// Segment boundaries found by one binary search per wave + sequential walk of
// the sorted segment array (wave-uniform scalar loads).
__global__ __launch_bounds__(256) void accumulate_nodes(
    const float* __restrict__ Wh,
    const float* __restrict__ Mh,
    const int* __restrict__ node_ids,
    const int* __restrict__ neighbor_ids,
    const int* __restrict__ segs,
    float* __restrict__ partials,
    int N, int E)
{
    const int lane = threadIdx.x & 63;
    const int wv   = threadIdx.x >> 6;     // wave id 0..3

    const int chunk = (N + (int)gridDim.x - 1) / (int)gridDim.x;
    const int nbeg  = blockIdx.x * chunk;
    const int nend  = min(N, nbeg + chunk);

    const float2* __restrict__ Wh2 = reinterpret_cast<const float2*>(Wh);
    const float2* __restrict__ Mh2 = reinterpret_cast<const float2*>(Mh);

    float accx = 0.f, accy = 0.f;

    const int cnt = nend - nbeg;
    if (cnt > 0) {
        const int per  = (cnt + 3) >> 2;
        const int wbeg = nbeg + wv * per;
        const int wend = min(nend, wbeg + per);
        if (wbeg < wend) {
            // lower_bound(segs, wbeg)
            int lo = 0, hi = E;
            while (lo < hi) {
                const int mid = (lo + hi) >> 1;
                if (segs[mid] < wbeg) lo = mid + 1; else hi = mid;
            }
            int e = lo;
            for (int i = wbeg; i < wend; ++i) {
                int eend = e;
                while (eend < E && segs[eend] == i) ++eend;

                const float2 base = Wh2[(size_t)node_ids[i] * 64 + lane];
                float s0x = 0.f, s0y = 0.f, s1x = 0.f, s1y = 0.f;
                float s2x = 0.f, s2y = 0.f, s3x = 0.f, s3y = 0.f;
                int ee = e;
                for (; ee + 4 <= eend; ee += 4) {
                    const int t0 = neighbor_ids[ee + 0];
                    const int t1 = neighbor_ids[ee + 1];
                    const int t2 = neighbor_ids[ee + 2];
                    const int t3 = neighbor_ids[ee + 3];
                    const float2 a0 = Mh2[(size_t)t0 * 64 + lane];
                    const float2 a1 = Mh2[(size_t)t1 * 64 + lane];
                    const float2 a2 = Mh2[(size_t)t2 * 64 + lane];
                    const float2 a3 = Mh2[(size_t)t3 * 64 + lane];
                    s0x += a0.x; s0y += a0.y;
                    s1x += a1.x; s1y += a1.y;
                    s2x += a2.x; s2y += a2.y;
                    s3x += a3.x; s3y += a3.y;
                }
                for (; ee < eend; ++ee) {
                    const int t0 = neighbor_ids[ee];
                    const float2 a0 = Mh2[(size_t)t0 * 64 + lane];
                    s0x += a0.x; s0y += a0.y;
                }
                const float px = base.x + ((s0x + s1x) + (s2x + s3x));
                const float py = base.y + ((s0y + s1y) + (s2y + s3y));
                accx += fmaxf(px, 0.f);
                accy += fmaxf(py, 0.f);
                e = eend;
            }
        }
    }

    __shared__ float red[4][DDIM];
    red[wv][lane * 2 + 0] = accx;
    red[wv][lane * 2 + 1] = accy;
    __syncthreads();
    if (threadIdx.x < DDIM) {
        const float v = red[0][threadIdx.x] + red[1][threadIdx.x]
                      + red[2][threadIdx.x] + red[3][threadIdx.x];
        partials[(size_t)blockIdx.x * DDIM + threadIdx.x] = v;
    }
}

// ---------------- Kernel 3: reduce partials + softmax ----------------
__global__ __launch_bounds__(1024) void finalize_softmax(
    const float* __restrict__ partials, float* __restrict__ out, int nb)
{
    const int t = threadIdx.x;
    const int d = t & (DDIM - 1);
    const int g = t >> 7;                  // 0..7

    float s = 0.f;
    for (int b = g; b < nb; b += 8)
        s += partials[(size_t)b * DDIM + d];

    __shared__ float red[8][DDIM];
    red[g][d] = s;
    __syncthreads();

    __shared__ float vec[DDIM];
    __shared__ float tmp[DDIM];
    if (g == 0) {
        float v = 0.f;
#pragma unroll
        for (int g2 = 0; g2 < 8; ++g2) v += red[g2][d];
        vec[d] = v;
    }
    __syncthreads();

    const float sv = vec[d];
    if (g == 0) tmp[d] = sv;
    __syncthreads();
    for (int off = 64; off > 0; off >>= 1) {
        if (t < off) tmp[t] = fmaxf(tmp[t], tmp[t + off]);
        __syncthreads();
    }
    const float mx = tmp[0];
    __syncthreads();
    const float ev = expf(sv - mx);
    if (g == 0) tmp[d] = ev;
    __syncthreads();
    for (int off = 64; off > 0; off >>= 1) {
        if (t < off) tmp[t] += tmp[t + off];
        __syncthreads();
    }
    if (g == 0) out[d] = ev / tmp[0];
}

extern "C" void kernel_launch(void* const* d_in, const int* in_sizes, int n_in,
                              void* d_out, int out_size, void* d_ws, size_t ws_size,
                              hipStream_t stream) {
    const float* impact        = (const float*)d_in[0];
    const float* W             = (const float*)d_in[1];
    const float* Mm            = (const float*)d_in[2];
    const int*   node_ids      = (const int*)d_in[3];
    const int*   neighbor_ids  = (const int*)d_in[4];
    const int*   neighbor_segs = (const int*)d_in[5];

    const int T = in_sizes[0] / DDIM;   // 10000
    const int N = in_sizes[3];          // 50000
    const int E = in_sizes[4];          // 800000

    char* ws = (char*)d_ws;
    float* Wh       = (float*)ws;
    float* Mh       = (float*)(ws + (size_t)T * DDIM * sizeof(float));
    float* partials = (float*)(ws + 2u * (size_t)T * DDIM * sizeof(float));
    float* outf     = (float*)d_out;

    precompute_wh_mh<<<(T + 7) / 8, 128, 0, stream>>>(impact, W, Mm, Wh, Mh, T);
    accumulate_nodes<<<ACC_BLOCKS, 256, 0, stream>>>(Wh, Mh, node_ids, neighbor_ids,
                                                     neighbor_segs, partials, N, E);
    finalize_softmax<<<1, 1024, 0, stream>>>(partials, outf, ACC_BLOCKS);
}

// Round 4
// 145.903 us; speedup vs baseline: 1.3350x; 1.3350x over previous
//
#include <hip/hip_runtime.h>

#define DDIM 128
#define ACC_BLOCKS 2048   // 2048 blocks x 4 waves = 8192 waves = 100% occupancy potential

// ---------------- Kernel 0: CSR rowptr from sorted segment ids ----------------
// rowptr[i] = first edge e with segs[e] >= i  (i in [0, N]); rowptr[N] = E.
__global__ __launch_bounds__(256) void build_rowptr(
    const int* __restrict__ segs, int* __restrict__ rowptr, int N, int E)
{
    const int e = blockIdx.x * blockDim.x + threadIdx.x;
    if (e >= E) return;
    const int sc = segs[e];
    const int sp = (e == 0) ? -1 : segs[e - 1];
    for (int i = sp + 1; i <= sc; ++i) rowptr[i] = e;
    if (e == E - 1) {
        for (int i = sc + 1; i <= N; ++i) rowptr[i] = E;
    }
}

// ---------------- Kernel 1: Wh[t] = W @ h[t], Mh[t] = M @ h[t] ----------------
// 8 impact rows staged in LDS (coalesced); thread d owns output feature d and
// streams its W/M rows as float4 (L1/L2 resident).
__global__ __launch_bounds__(128) void precompute_wh_mh(
    const float* __restrict__ impact,
    const float* __restrict__ W,
    const float* __restrict__ Mm,
    float* __restrict__ Wh,
    float* __restrict__ Mh,
    int T)
{
    __shared__ float hrow[8][DDIM];
    const int d = threadIdx.x;                 // output feature
    const int row0 = blockIdx.x * 8;
    const int rmax = min(8, T - row0);
    if (rmax <= 0) return;

    for (int r = 0; r < rmax; ++r)
        hrow[r][d] = impact[(size_t)(row0 + r) * DDIM + d];   // coalesced
    __syncthreads();

    const float4* __restrict__ W4 = reinterpret_cast<const float4*>(W) + (size_t)d * 32;
    const float4* __restrict__ M4 = reinterpret_cast<const float4*>(Mm) + (size_t)d * 32;
    const float4* __restrict__ H4 = reinterpret_cast<const float4*>(&hrow[0][0]);

    float accW[8], accM[8];
#pragma unroll
    for (int r = 0; r < 8; ++r) { accW[r] = 0.f; accM[r] = 0.f; }

    for (int kq = 0; kq < 32; ++kq) {
        const float4 wv = W4[kq];
        const float4 mv = M4[kq];
#pragma unroll
        for (int r = 0; r < 8; ++r) {
            const float4 hv = H4[r * 32 + kq];   // LDS broadcast, conflict-free
            accW[r] = fmaf(hv.x, wv.x, accW[r]);
            accW[r] = fmaf(hv.y, wv.y, accW[r]);
            accW[r] = fmaf(hv.z, wv.z, accW[r]);
            accW[r] = fmaf(hv.w, wv.w, accW[r]);
            accM[r] = fmaf(hv.x, mv.x, accM[r]);
            accM[r] = fmaf(hv.y, mv.y, accM[r]);
            accM[r] = fmaf(hv.z, mv.z, accM[r]);
            accM[r] = fmaf(hv.w, mv.w, accM[r]);
        }
    }
    for (int r = 0; r < rmax; ++r) {
        Wh[(size_t)(row0 + r) * DDIM + d] = accW[r];
        Mh[(size_t)(row0 + r) * DDIM + d] = accM[r];
    }
}

// ---------------- Kernel 2: per-node gather-sum + relu + block partial ----------------
// 8192 waves, each owns a contiguous node range via rowptr (no seg walk, no
// binary search). Lane = float2 of features; one wave gather = one 512B row.
// 8 gathers in flight via unroll.
__global__ __launch_bounds__(256) void accumulate_nodes(
    const float* __restrict__ Wh,
    const float* __restrict__ Mh,
    const int* __restrict__ node_ids,
    const int* __restrict__ neighbor_ids,
    const int* __restrict__ rowptr,
    float* __restrict__ partials,
    int N)
{
    const int lane = threadIdx.x & 63;
    const int wv   = threadIdx.x >> 6;     // wave id 0..3
    const int wg   = blockIdx.x * 4 + wv;  // global wave id
    const int nwaves = (int)gridDim.x * 4;
    const int per  = (N + nwaves - 1) / nwaves;
    const int wbeg = wg * per;
    const int wend = min(N, wbeg + per);

    const float2* __restrict__ Wh2 = reinterpret_cast<const float2*>(Wh);
    const float2* __restrict__ Mh2 = reinterpret_cast<const float2*>(Mh);

    float accx = 0.f, accy = 0.f;

    if (wbeg < wend) {
        int e = rowptr[wbeg];
        for (int i = wbeg; i < wend; ++i) {
            const int eend = rowptr[i + 1];
            const float2 base = Wh2[(size_t)node_ids[i] * 64 + lane];
            float s0x = 0.f, s0y = 0.f, s1x = 0.f, s1y = 0.f;
            float s2x = 0.f, s2y = 0.f, s3x = 0.f, s3y = 0.f;
            float s4x = 0.f, s4y = 0.f, s5x = 0.f, s5y = 0.f;
            float s6x = 0.f, s6y = 0.f, s7x = 0.f, s7y = 0.f;
            int ee = e;
            for (; ee + 8 <= eend; ee += 8) {
                const int t0 = neighbor_ids[ee + 0];
                const int t1 = neighbor_ids[ee + 1];
                const int t2 = neighbor_ids[ee + 2];
                const int t3 = neighbor_ids[ee + 3];
                const int t4 = neighbor_ids[ee + 4];
                const int t5 = neighbor_ids[ee + 5];
                const int t6 = neighbor_ids[ee + 6];
                const int t7 = neighbor_ids[ee + 7];
                const float2 a0 = Mh2[(size_t)t0 * 64 + lane];
                const float2 a1 = Mh2[(size_t)t1 * 64 + lane];
                const float2 a2 = Mh2[(size_t)t2 * 64 + lane];
                const float2 a3 = Mh2[(size_t)t3 * 64 + lane];
                const float2 a4 = Mh2[(size_t)t4 * 64 + lane];
                const float2 a5 = Mh2[(size_t)t5 * 64 + lane];
                const float2 a6 = Mh2[(size_t)t6 * 64 + lane];
                const float2 a7 = Mh2[(size_t)t7 * 64 + lane];
                s0x += a0.x; s0y += a0.y;
                s1x += a1.x; s1y += a1.y;
                s2x += a2.x; s2y += a2.y;
                s3x += a3.x; s3y += a3.y;
                s4x += a4.x; s4y += a4.y;
                s5x += a5.x; s5y += a5.y;
                s6x += a6.x; s6y += a6.y;
                s7x += a7.x; s7y += a7.y;
            }
            for (; ee < eend; ++ee) {
                const int t0 = neighbor_ids[ee];
                const float2 a0 = Mh2[(size_t)t0 * 64 + lane];
                s0x += a0.x; s0y += a0.y;
            }
            const float px = base.x + (((s0x + s1x) + (s2x + s3x)) + ((s4x + s5x) + (s6x + s7x)));
            const float py = base.y + (((s0y + s1y) + (s2y + s3y)) + ((s4y + s5y) + (s6y + s7y)));
            accx += fmaxf(px, 0.f);
            accy += fmaxf(py, 0.f);
            e = eend;
        }
    }

    __shared__ float red[4][DDIM];
    red[wv][lane * 2 + 0] = accx;
    red[wv][lane * 2 + 1] = accy;
    __syncthreads();
    if (threadIdx.x < DDIM) {
        const float v = red[0][threadIdx.x] + red[1][threadIdx.x]
                      + red[2][threadIdx.x] + red[3][threadIdx.x];
        partials[(size_t)blockIdx.x * DDIM + threadIdx.x] = v;
    }
}

// ---------------- Kernel 3: reduce partials + softmax ----------------
__global__ __launch_bounds__(1024) void finalize_softmax(
    const float* __restrict__ partials, float* __restrict__ out, int nb)
{
    const int t = threadIdx.x;
    const int d = t & (DDIM - 1);
    const int g = t >> 7;                  // 0..7

    float s = 0.f;
    for (int b = g; b < nb; b += 8)
        s += partials[(size_t)b * DDIM + d];

    __shared__ float red[8][DDIM];
    red[g][d] = s;
    __syncthreads();

    __shared__ float vec[DDIM];
    __shared__ float tmp[DDIM];
    if (g == 0) {
        float v = 0.f;
#pragma unroll
        for (int g2 = 0; g2 < 8; ++g2) v += red[g2][d];
        vec[d] = v;
    }
    __syncthreads();

    const float sv = vec[d];
    if (g == 0) tmp[d] = sv;
    __syncthreads();
    for (int off = 64; off > 0; off >>= 1) {
        if (t < off) tmp[t] = fmaxf(tmp[t], tmp[t + off]);
        __syncthreads();
    }
    const float mx = tmp[0];
    __syncthreads();
    const float ev = expf(sv - mx);
    if (g == 0) tmp[d] = ev;
    __syncthreads();
    for (int off = 64; off > 0; off >>= 1) {
        if (t < off) tmp[t] += tmp[t + off];
        __syncthreads();
    }
    if (g == 0) out[d] = ev / tmp[0];
}

extern "C" void kernel_launch(void* const* d_in, const int* in_sizes, int n_in,
                              void* d_out, int out_size, void* d_ws, size_t ws_size,
                              hipStream_t stream) {
    const float* impact        = (const float*)d_in[0];
    const float* W             = (const float*)d_in[1];
    const float* Mm            = (const float*)d_in[2];
    const int*   node_ids      = (const int*)d_in[3];
    const int*   neighbor_ids  = (const int*)d_in[4];
    const int*   neighbor_segs = (const int*)d_in[5];

    const int T = in_sizes[0] / DDIM;   // 10000
    const int N = in_sizes[3];          // 50000
    const int E = in_sizes[4];          // 800000

    char* ws = (char*)d_ws;
    size_t off = 0;
    float* Wh       = (float*)(ws + off); off += (size_t)T * DDIM * sizeof(float);
    float* Mh       = (float*)(ws + off); off += (size_t)T * DDIM * sizeof(float);
    float* partials = (float*)(ws + off); off += (size_t)ACC_BLOCKS * DDIM * sizeof(float);
    int*   rowptr   = (int*)(ws + off);   off += (size_t)(N + 1) * sizeof(int);
    float* outf     = (float*)d_out;

    build_rowptr<<<(E + 255) / 256, 256, 0, stream>>>(neighbor_segs, rowptr, N, E);
    precompute_wh_mh<<<(T + 7) / 8, 128, 0, stream>>>(impact, W, Mm, Wh, Mh, T);
    accumulate_nodes<<<ACC_BLOCKS, 256, 0, stream>>>(Wh, Mh, node_ids, neighbor_ids,
                                                     rowptr, partials, N);
    finalize_softmax<<<1, 1024, 0, stream>>>(partials, outf, ACC_BLOCKS);
}

// Round 5
// 90.354 us; speedup vs baseline: 2.1558x; 1.6148x over previous
//
#include <hip/hip_runtime.h>

#define DDIM 128
#define ACC_BLOCKS 2048   // 2048 blocks x 4 waves = 8192 waves = 100% occupancy potential
#define RED_BLOCKS 64     // partials reduction spread over 64 CUs

// ---------------- Kernel 0: CSR rowptr from sorted segment ids ----------------
// rowptr[i] = first edge e with segs[e] >= i  (i in [0, N]); rowptr[N] = E.
__global__ __launch_bounds__(256) void build_rowptr(
    const int* __restrict__ segs, int* __restrict__ rowptr, int N, int E)
{
    const int e = blockIdx.x * blockDim.x + threadIdx.x;
    if (e >= E) return;
    const int sc = segs[e];
    const int sp = (e == 0) ? -1 : segs[e - 1];
    for (int i = sp + 1; i <= sc; ++i) rowptr[i] = e;
    if (e == E - 1) {
        for (int i = sc + 1; i <= N; ++i) rowptr[i] = E;
    }
}

// ---------------- Kernel 1: Wh[t] = W @ h[t], Mh[t] = M @ h[t] ----------------
__global__ __launch_bounds__(128) void precompute_wh_mh(
    const float* __restrict__ impact,
    const float* __restrict__ W,
    const float* __restrict__ Mm,
    float* __restrict__ Wh,
    float* __restrict__ Mh,
    int T)
{
    __shared__ float hrow[8][DDIM];
    const int d = threadIdx.x;                 // output feature
    const int row0 = blockIdx.x * 8;
    const int rmax = min(8, T - row0);
    if (rmax <= 0) return;

    for (int r = 0; r < rmax; ++r)
        hrow[r][d] = impact[(size_t)(row0 + r) * DDIM + d];   // coalesced
    __syncthreads();

    const float4* __restrict__ W4 = reinterpret_cast<const float4*>(W) + (size_t)d * 32;
    const float4* __restrict__ M4 = reinterpret_cast<const float4*>(Mm) + (size_t)d * 32;
    const float4* __restrict__ H4 = reinterpret_cast<const float4*>(&hrow[0][0]);

    float accW[8], accM[8];
#pragma unroll
    for (int r = 0; r < 8; ++r) { accW[r] = 0.f; accM[r] = 0.f; }

    for (int kq = 0; kq < 32; ++kq) {
        const float4 wv = W4[kq];
        const float4 mv = M4[kq];
#pragma unroll
        for (int r = 0; r < 8; ++r) {
            const float4 hv = H4[r * 32 + kq];   // LDS broadcast, conflict-free
            accW[r] = fmaf(hv.x, wv.x, accW[r]);
            accW[r] = fmaf(hv.y, wv.y, accW[r]);
            accW[r] = fmaf(hv.z, wv.z, accW[r]);
            accW[r] = fmaf(hv.w, wv.w, accW[r]);
            accM[r] = fmaf(hv.x, mv.x, accM[r]);
            accM[r] = fmaf(hv.y, mv.y, accM[r]);
            accM[r] = fmaf(hv.z, mv.z, accM[r]);
            accM[r] = fmaf(hv.w, mv.w, accM[r]);
        }
    }
    for (int r = 0; r < rmax; ++r) {
        Wh[(size_t)(row0 + r) * DDIM + d] = accW[r];
        Mh[(size_t)(row0 + r) * DDIM + d] = accM[r];
    }
}

// ---------------- Kernel 2: per-node gather-sum + relu + block partial ----------------
__global__ __launch_bounds__(256) void accumulate_nodes(
    const float* __restrict__ Wh,
    const float* __restrict__ Mh,
    const int* __restrict__ node_ids,
    const int* __restrict__ neighbor_ids,
    const int* __restrict__ rowptr,
    float* __restrict__ partials,
    int N)
{
    const int lane = threadIdx.x & 63;
    const int wv   = threadIdx.x >> 6;     // wave id 0..3
    const int wg   = blockIdx.x * 4 + wv;  // global wave id
    const int nwaves = (int)gridDim.x * 4;
    const int per  = (N + nwaves - 1) / nwaves;
    const int wbeg = wg * per;
    const int wend = min(N, wbeg + per);

    const float2* __restrict__ Wh2 = reinterpret_cast<const float2*>(Wh);
    const float2* __restrict__ Mh2 = reinterpret_cast<const float2*>(Mh);

    float accx = 0.f, accy = 0.f;

    if (wbeg < wend) {
        int e = rowptr[wbeg];
        for (int i = wbeg; i < wend; ++i) {
            const int eend = rowptr[i + 1];
            const float2 base = Wh2[(size_t)node_ids[i] * 64 + lane];
            float s0x = 0.f, s0y = 0.f, s1x = 0.f, s1y = 0.f;
            float s2x = 0.f, s2y = 0.f, s3x = 0.f, s3y = 0.f;
            float s4x = 0.f, s4y = 0.f, s5x = 0.f, s5y = 0.f;
            float s6x = 0.f, s6y = 0.f, s7x = 0.f, s7y = 0.f;
            int ee = e;
            for (; ee + 8 <= eend; ee += 8) {
                const int t0 = neighbor_ids[ee + 0];
                const int t1 = neighbor_ids[ee + 1];
                const int t2 = neighbor_ids[ee + 2];
                const int t3 = neighbor_ids[ee + 3];
                const int t4 = neighbor_ids[ee + 4];
                const int t5 = neighbor_ids[ee + 5];
                const int t6 = neighbor_ids[ee + 6];
                const int t7 = neighbor_ids[ee + 7];
                const float2 a0 = Mh2[(size_t)t0 * 64 + lane];
                const float2 a1 = Mh2[(size_t)t1 * 64 + lane];
                const float2 a2 = Mh2[(size_t)t2 * 64 + lane];
                const float2 a3 = Mh2[(size_t)t3 * 64 + lane];
                const float2 a4 = Mh2[(size_t)t4 * 64 + lane];
                const float2 a5 = Mh2[(size_t)t5 * 64 + lane];
                const float2 a6 = Mh2[(size_t)t6 * 64 + lane];
                const float2 a7 = Mh2[(size_t)t7 * 64 + lane];
                s0x += a0.x; s0y += a0.y;
                s1x += a1.x; s1y += a1.y;
                s2x += a2.x; s2y += a2.y;
                s3x += a3.x; s3y += a3.y;
                s4x += a4.x; s4y += a4.y;
                s5x += a5.x; s5y += a5.y;
                s6x += a6.x; s6y += a6.y;
                s7x += a7.x; s7y += a7.y;
            }
            for (; ee < eend; ++ee) {
                const int t0 = neighbor_ids[ee];
                const float2 a0 = Mh2[(size_t)t0 * 64 + lane];
                s0x += a0.x; s0y += a0.y;
            }
            const float px = base.x + (((s0x + s1x) + (s2x + s3x)) + ((s4x + s5x) + (s6x + s7x)));
            const float py = base.y + (((s0y + s1y) + (s2y + s3y)) + ((s4y + s5y) + (s6y + s7y)));
            accx += fmaxf(px, 0.f);
            accy += fmaxf(py, 0.f);
            e = eend;
        }
    }

    __shared__ float red[4][DDIM];
    red[wv][lane * 2 + 0] = accx;
    red[wv][lane * 2 + 1] = accy;
    __syncthreads();
    if (threadIdx.x < DDIM) {
        const float v = red[0][threadIdx.x] + red[1][threadIdx.x]
                      + red[2][threadIdx.x] + red[3][threadIdx.x];
        partials[(size_t)blockIdx.x * DDIM + threadIdx.x] = v;
    }
}

// ---------------- Kernel 3a: grid-parallel partials reduction ----------------
// 64 blocks x 256 threads; block b sums rows [b*32, b*32+32) -> out2[b][d].
__global__ __launch_bounds__(256) void reduce_partials(
    const float* __restrict__ partials, float* __restrict__ out2, int nb)
{
    const int d = threadIdx.x & (DDIM - 1);
    const int h = threadIdx.x >> 7;              // 0..1
    const int rows = nb / RED_BLOCKS;            // 32
    const int r0 = blockIdx.x * rows;
    float s = 0.f;
    for (int r = r0 + h; r < r0 + rows; r += 2)
        s += partials[(size_t)r * DDIM + d];     // coalesced 512B rows
    __shared__ float red[2][DDIM];
    red[h][d] = s;
    __syncthreads();
    if (threadIdx.x < DDIM)
        out2[(size_t)blockIdx.x * DDIM + threadIdx.x] =
            red[0][threadIdx.x] + red[1][threadIdx.x];
}

// ---------------- Kernel 3b: final reduce (64 rows) + softmax ----------------
__global__ __launch_bounds__(1024) void finalize_softmax(
    const float* __restrict__ p2, float* __restrict__ out, int nb)
{
    const int t = threadIdx.x;
    const int d = t & (DDIM - 1);
    const int g = t >> 7;                  // 0..7

    float s = 0.f;
    for (int b = g; b < nb; b += 8)
        s += p2[(size_t)b * DDIM + d];

    __shared__ float red[8][DDIM];
    red[g][d] = s;
    __syncthreads();

    __shared__ float vec[DDIM];
    __shared__ float tmp[DDIM];
    if (g == 0) {
        float v = 0.f;
#pragma unroll
        for (int g2 = 0; g2 < 8; ++g2) v += red[g2][d];
        vec[d] = v;
    }
    __syncthreads();

    const float sv = vec[d];
    if (g == 0) tmp[d] = sv;
    __syncthreads();
    for (int off = 64; off > 0; off >>= 1) {
        if (t < off) tmp[t] = fmaxf(tmp[t], tmp[t + off]);
        __syncthreads();
    }
    const float mx = tmp[0];
    __syncthreads();
    const float ev = expf(sv - mx);
    if (g == 0) tmp[d] = ev;
    __syncthreads();
    for (int off = 64; off > 0; off >>= 1) {
        if (t < off) tmp[t] += tmp[t + off];
        __syncthreads();
    }
    if (g == 0) out[d] = ev / tmp[0];
}

extern "C" void kernel_launch(void* const* d_in, const int* in_sizes, int n_in,
                              void* d_out, int out_size, void* d_ws, size_t ws_size,
                              hipStream_t stream) {
    const float* impact        = (const float*)d_in[0];
    const float* W             = (const float*)d_in[1];
    const float* Mm            = (const float*)d_in[2];
    const int*   node_ids      = (const int*)d_in[3];
    const int*   neighbor_ids  = (const int*)d_in[4];
    const int*   neighbor_segs = (const int*)d_in[5];

    const int T = in_sizes[0] / DDIM;   // 10000
    const int N = in_sizes[3];          // 50000
    const int E = in_sizes[4];          // 800000

    char* ws = (char*)d_ws;
    size_t off = 0;
    float* Wh       = (float*)(ws + off); off += (size_t)T * DDIM * sizeof(float);
    float* Mh       = (float*)(ws + off); off += (size_t)T * DDIM * sizeof(float);
    float* partials = (float*)(ws + off); off += (size_t)ACC_BLOCKS * DDIM * sizeof(float);
    float* part2    = (float*)(ws + off); off += (size_t)RED_BLOCKS * DDIM * sizeof(float);
    int*   rowptr   = (int*)(ws + off);   off += (size_t)(N + 1) * sizeof(int);
    float* outf     = (float*)d_out;

    build_rowptr<<<(E + 255) / 256, 256, 0, stream>>>(neighbor_segs, rowptr, N, E);
    precompute_wh_mh<<<(T + 7) / 8, 128, 0, stream>>>(impact, W, Mm, Wh, Mh, T);
    accumulate_nodes<<<ACC_BLOCKS, 256, 0, stream>>>(Wh, Mh, node_ids, neighbor_ids,
                                                     rowptr, partials, N);
    reduce_partials<<<RED_BLOCKS, 256, 0, stream>>>(partials, part2, ACC_BLOCKS);
    finalize_softmax<<<1, 1024, 0, stream>>>(part2, outf, RED_BLOCKS);
}